// Round 5
// baseline (590.540 us; speedup 1.0000x reference)
//
#include <hip/hip_runtime.h>

// y = x @ (weight * blockscale)^T ; x[8192,4096] f32, weight[4096,4096] f32,
// w_scale[32,32] f32, out f32 [8192,4096].
#define M_DIM 8192
#define K_DIM 4096
#define O_DIM 4096
#define QB    128
#define BK    64     // K per tile
#define BMT   256    // 256x256 output tile, 8 waves (2M x 4N)
#define BNT   256

typedef __attribute__((ext_vector_type(8))) short  short8;   // 8 bf16
typedef __attribute__((ext_vector_type(4))) float  floatx4;  // MFMA acc

#define AS1 __attribute__((address_space(1)))
#define AS3 __attribute__((address_space(3)))

// fp32 -> bf16 bits, round-to-nearest-even
__device__ __forceinline__ short f2bf(float f) {
    unsigned u = __float_as_uint(f);
    unsigned r = u + 0x7fffu + ((u >> 16) & 1u);
    return (short)(r >> 16);
}

// ---- fused pre-pass: x -> bf16, weight*scale -> bf16, one dispatch ----
__global__ __launch_bounds__(512) void cvt_fused(const float* __restrict__ x,
                                                 const float* __restrict__ w,
                                                 const float* __restrict__ s,
                                                 short* __restrict__ xb,
                                                 short* __restrict__ wb) {
    const size_t NX = (size_t)M_DIM * K_DIM / 8;   // x threads
    size_t t = (size_t)blockIdx.x * 512 + threadIdx.x;
    if (t < NX) {
        size_t i = t * 8;
        floatx4 f0 = *(const floatx4*)(x + i);
        floatx4 f1 = *(const floatx4*)(x + i + 4);
        short8 o;
        o[0] = f2bf(f0[0]); o[1] = f2bf(f0[1]); o[2] = f2bf(f0[2]); o[3] = f2bf(f0[3]);
        o[4] = f2bf(f1[0]); o[5] = f2bf(f1[1]); o[6] = f2bf(f1[2]); o[7] = f2bf(f1[3]);
        *(short8*)(xb + i) = o;
    } else {
        size_t i = (t - NX) * 8;
        int o = (int)(i >> 12);            // / K_DIM
        int k = (int)(i & (K_DIM - 1));
        float sc = s[(o >> 7) * (K_DIM / QB) + (k >> 7)];
        floatx4 f0 = *(const floatx4*)(w + i);
        floatx4 f1 = *(const floatx4*)(w + i + 4);
        short8 v;
        v[0] = f2bf(f0[0] * sc); v[1] = f2bf(f0[1] * sc);
        v[2] = f2bf(f0[2] * sc); v[3] = f2bf(f0[3] * sc);
        v[4] = f2bf(f1[0] * sc); v[5] = f2bf(f1[1] * sc);
        v[6] = f2bf(f1[2] * sc); v[7] = f2bf(f1[3] * sc);
        *(short8*)(wb + i) = v;
    }
}

// ---- 256x256 bf16 GEMM: A staged in LDS, B loaded global->reg ----
// Cycle model (rounds 0-4): per K-tile per CU, MFMA ~2480 cyc; with BOTH
// operands through LDS, LDS pipe ~2800 cyc (192 ds_read_b128 + 64KiB writes)
// -> two saturated pipes, measured 4912 (poor overlap; 4 schedule variants
// all null). Fix: B is L2-resident (4MiB/XCD by the XCD map, 32x reuse) ->
// load B fragments DIRECTLY global->reg (8 dwordx4/wave/K-tile, per-lane
// addr = exact fragment layout, double-buffered 1 tile ahead). LDS traffic
// drops to ~1790 cyc < MFMA -> MFMA is the sole critical pipe. L2-line
// efficiency kept: each B-row's 128B line is fully consumed per K-tile;
// same-wc waves share rows via L1 (4 sets x 8KiB = 32KiB).
//
// Per K-tile T (buf c = T&1), 2 barriers only (A-buffer hazards):
//   RDA1(c); Q0(a0); Q1(a0); issue b(T+1)->reg;
//   lgkm(0); BARRIER;                 // all waves' a0,a1 reads retired
//   stage A(T+2)h0 -> c; Q2(a1); stage A(T+2)h1 -> c; Q3(a1);
//   vmcnt(12); BARRIER;               // A(T+1) confirmed; b(T+1)+A(T+2) fly
//   RDA0(n);                          // pre-read next tile's a0
// vmcnt(12) proof: queue = [A(T+1)4 | b(T+1)8 | A(T+2)4] = 16 -> leave 12.
// Compiler-inserted vmcnt before b-use drains at most loads issued >=1 tile
// earlier (harmless). A-prefetch depth: 2 tiles (~5000 cyc cover).
#define WLG0  asm volatile("s_waitcnt lgkmcnt(0)" ::: "memory")
#define WVM12 asm volatile("s_waitcnt vmcnt(12)" ::: "memory")
#define WVM8  asm volatile("s_waitcnt vmcnt(8)" ::: "memory")
#define WVM4  asm volatile("s_waitcnt vmcnt(4)" ::: "memory")
#define BARR  __builtin_amdgcn_s_barrier()
#define SCHEDB __builtin_amdgcn_sched_barrier(0)
#define SP1   __builtin_amdgcn_s_setprio(1)
#define SP0   __builtin_amdgcn_s_setprio(0)

#define LDA4(DST, BUF, ROFF)                                                    \
    _Pragma("unroll")                                                           \
    for (int mi = 0; mi < 4; ++mi) {                                            \
        DST[mi][0] = *(const short8*)&lsA[BUF][rA + (ROFF) + mi * 1024 + pc0];  \
        DST[mi][1] = *(const short8*)&lsA[BUF][rA + (ROFF) + mi * 1024 + pc1];  \
    }

#define RDA0(B) LDA4(a0, B, 0)
#define RDA1(B) LDA4(a1, B, 4096)

// b(T) fragments: lane reads B[bn*256 + wc*64 + ni*16 + frow][k0 + fc*8 + ks*32]
// = one dwordx4 per (ni,ks). 8 loads/wave/K-tile, plain (compiler-scheduled).
#define ISSUE_B(DST, KOFF)                                                      \
    _Pragma("unroll")                                                           \
    for (int ni = 0; ni < 4; ++ni)                                              \
        _Pragma("unroll")                                                       \
        for (int ks = 0; ks < 2; ++ks)                                          \
            DST[ni][ks] = *(const short8*)(gBF + (size_t)ni * 16 * K_DIM +      \
                                           (KOFF) + ks * 32);

// one C-quadrant: 2 col-frags (NB, NB+1) x full K -> 16 MFMA
#define MMQ(AF, BB, NB, MO, NO)                                                 \
    _Pragma("unroll")                                                           \
    for (int mi = 0; mi < 4; ++mi)                                              \
        _Pragma("unroll")                                                       \
        for (int ni = 0; ni < 2; ++ni)                                          \
            _Pragma("unroll")                                                   \
            for (int ks = 0; ks < 2; ++ks)                                      \
                acc[(MO) + mi][(NO) + ni] = __builtin_amdgcn_mfma_f32_16x16x32_bf16( \
                    AF[mi][ks], BB[(NB) + ni][ks], acc[(MO) + mi][(NO) + ni], 0, 0, 0);

#define STAGE(BUF, KOFF, H)                                                     \
    __builtin_amdgcn_global_load_lds(                                           \
        (const AS1 void*)(gA + (size_t)((H) * 128) * K_DIM + (KOFF)),           \
        (AS3 void*)&lsA[BUF][(H) * 128 * BK + dst], 16, 0, 0);                  \
    __builtin_amdgcn_global_load_lds(                                           \
        (const AS1 void*)(gA + (size_t)((H) * 128 + 64) * K_DIM + (KOFF)),      \
        (AS3 void*)&lsA[BUF][((H) * 128 + 64) * BK + dst], 16, 0, 0);

// full K-tile: c = A-buf, n = next buf, BC = cur b-regs, BN = next b-regs
#define TILE(c, n, BC, BN, KB, KA)                                              \
    RDA1(c);                                                                    \
    SP1; MMQ(a0, BC, 0, 0, 0) MMQ(a0, BC, 2, 0, 2) SP0;                         \
    ISSUE_B(BN, KB)                                                             \
    WLG0; BARR; SCHEDB;                                                         \
    STAGE(c, KA, 0)                                                             \
    SP1; MMQ(a1, BC, 0, 4, 0) SP0;                                              \
    STAGE(c, KA, 1)                                                             \
    SP1; MMQ(a1, BC, 2, 4, 2) SP0;                                              \
    WVM12; BARR; SCHEDB;                                                        \
    RDA0(n);

__global__ __launch_bounds__(512, 2) void gemm_bt(const short* __restrict__ A,
                                                  const short* __restrict__ B,
                                                  float* __restrict__ C) {
    __shared__ __align__(16) short lsA[2][BMT * BK];   // 64 KiB total

    const int tid  = threadIdx.x;
    const int lane = tid & 63;
    const int wave = tid >> 6;
    const int wr   = wave >> 2;     // 0..1
    const int wc   = wave & 3;      // 0..3

    // bijective XCD map: 512 blocks, 64 per XCD; XCD x owns bn stripe
    // {2x, 2x+1} (4 MiB of B in its L2); consecutive j alternate bn.
    const int id  = blockIdx.x;
    const int xcd = id & 7;
    const int j   = id >> 3;
    const int bm  = j >> 1;                  // 0..31
    const int bn  = (xcd << 1) | (j & 1);    // 0..15

    // A staging: thread covers row sr=tid>>3, phys chunk tid&7; logical chunk
    // (tid&7)^(sr&7) (invariant under row+64/128); dest lane-linear.
    const int sr  = tid >> 3;
    const int csw = ((tid & 7) ^ (sr & 7)) << 3;
    const int dst = tid * 8;
    const short* gA = A + (size_t)(bm * BMT + sr) * K_DIM + csw;

    // B fragment base: row = bn*256 + wc*64 + frow, col base fc*8
    const int frow = lane & 15;
    const int fc   = lane >> 4;
    const short* gBF = B + (size_t)(bn * BNT + wc * 64 + frow) * K_DIM + fc * 8;

    // A fragment reads (chunk-XOR swizzle matches staging)
    const int fsw  = frow & 7;
    const int pc0  = (fc ^ fsw) << 3;        // ks=0 physical chunk * 8
    const int pc1  = ((4 + fc) ^ fsw) << 3;  // ks=1
    const int rA   = (wr * 128 + frow) * BK;

    floatx4 acc[8][4];
#pragma unroll
    for (int mi = 0; mi < 8; ++mi)
#pragma unroll
        for (int ni = 0; ni < 4; ++ni)
            acc[mi][ni] = (floatx4){0.f, 0.f, 0.f, 0.f};

    short8 a0[4][2], a1[4][2], bA[4][2], bB[4][2];

    // prologue: b(0)->bA (8), A(0)->buf0 (4), A(1)->buf1 (4);
    // vmcnt(4) confirms b(0)+A(0), leaves A(1) in flight; pre-read a0.
    ISSUE_B(bA, 0)
    STAGE(0, 0, 0)
    STAGE(0, 0, 1)
    STAGE(1, 64, 0)
    STAGE(1, 64, 1)
    WVM4; BARR; SCHEDB;
    RDA0(0);

#pragma unroll 1
    for (int it = 0; it < 31; ++it) {
        TILE(0, 1, bA, bB, 64, 128)     // tile 2i:  stages A(2i+2), b(2i+1)
        TILE(1, 0, bB, bA, 128, 192)    // tile 2i+1: stages A(2i+3), b(2i+2)
        gA  += 128;
        gBF += 128;
    }

    // tile 62 (buf0, bA): issue b(63); no A-stage; confirm A(63) (leave b63).
    RDA1(0);
    SP1; MMQ(a0, bA, 0, 0, 0) MMQ(a0, bA, 2, 0, 2) SP0;
    ISSUE_B(bB, 64)
    WLG0; BARR; SCHEDB;
    SP1; MMQ(a1, bA, 0, 4, 0) MMQ(a1, bA, 2, 4, 2) SP0;
    WVM8; BARR; SCHEDB;
    RDA0(1);

    // tile 63 (buf1, bB): compiler inserts the b(63) wait.
    RDA1(1);
    SP1; MMQ(a0, bB, 0, 0, 0) MMQ(a0, bB, 2, 0, 2) SP0;
    WLG0;
    SP1; MMQ(a1, bB, 0, 4, 0) MMQ(a1, bB, 2, 4, 2) SP0;

    // Epilogue. C/D layout: col = lane&15, row = (lane>>4)*4 + reg.
    // Plain stores (NT regressed: +34MB HBM writes, +14us in round 4).
    const int quad  = lane >> 4;
    const int crow0 = bm * BMT + wr * 128 + quad * 4;
    const int ccol0 = bn * BNT + wc * 64 + frow;
#pragma unroll
    for (int mi = 0; mi < 8; ++mi)
#pragma unroll
        for (int ni = 0; ni < 4; ++ni) {
            float* cp = C + (size_t)(crow0 + mi * 16) * O_DIM + (ccol0 + ni * 16);
#pragma unroll
            for (int r = 0; r < 4; ++r)
                cp[(size_t)r * O_DIM] = acc[mi][ni][r];
        }
}

extern "C" void kernel_launch(void* const* d_in, const int* in_sizes, int n_in,
                              void* d_out, int out_size, void* d_ws, size_t ws_size,
                              hipStream_t stream) {
    const float* x  = (const float*)d_in[0];
    const float* w  = (const float*)d_in[1];
    const float* ws = (const float*)d_in[2];
    float* out = (float*)d_out;

    short* xb = (short*)d_ws;                       // 64 MiB bf16 x
    short* wb = xb + (size_t)M_DIM * K_DIM;         // 32 MiB bf16 dequant w

    const size_t total_t = ((size_t)M_DIM * K_DIM + (size_t)O_DIM * K_DIM) / 8;
    cvt_fused<<<(unsigned)(total_t / 512), 512, 0, stream>>>(x, w, ws, xb, wb);

    gemm_bt<<<(M_DIM / BMT) * (O_DIM / BNT), 512, 0, stream>>>(xb, wb, out);
}